// Round 15
// baseline (130.173 us; speedup 1.0000x reference)
//
#include <hip/hip_runtime.h>

#define SS 730
#define GG 4000
#define LENF 15
#define PD 10          // prefetch depth (steps); 730 % 10 == 0
#define GPAD 4032      // 63 waves per instance -> no wave mixes models
#define TT 10          // route time-tile (atomic-fallback path only)
#define RTT 73         // LDS-route time-tile; 730 = 73 * 10
#define RG 128         // LDS-route g-tile (128 threads/block)
#define NGT ((GG + RG - 1) / RG)      // 32 g-tiles
#define QN ((size_t)SS * GG)
#define QNI ((int)(SS * GG))

// ---------------------------------------------------------------------------
// Scan kernel: round-7 EXACT (proven floor ~88.7 us = ~290 cyc/step =
// max(issue ~177, chain ~290); bracketed by rounds 4/8/10/11/13/14 from all
// directions -- keep the body small, single-chain, PD-deep prefetch).
// One thread per (g, m, model); 4 slices, plain stores.
// ---------------------------------------------------------------------------
template<bool STORE4>
__global__ __launch_bounds__(64, 1) void hydro_scan(const float* __restrict__ x,
                                                    const float* __restrict__ raw,
                                                    float* __restrict__ qsim) {
    int tid = blockIdx.x * 64 + threadIdx.x;
    int g = tid % GPAD;
    int inst = tid / GPAD;
    if (g >= GG) return;
    int m = inst & 1;
    const float* pr = raw + (size_t)g * 38 + m;   // pr[2*i] = raw[g, i*2+m]

    int xoff = g * 3;
    int qoff = g + (STORE4 ? inst * QNI : 0);

    // prefetch pipeline: steps 0..PD-1
    float pb[PD], tb[PD], eb[PD];
#pragma unroll
    for (int j = 0; j < PD; ++j) {
        pb[j] = x[xoff]; tb[j] = x[xoff + 1]; eb[j] = x[xoff + 2];
        xoff += 3 * GG;
    }

    if (inst < 2) {
        // ---- HBV parameters (descale + derived constants) ----
        float beta  = 1.0f   + pr[0]  * 5.0f;
        float fc    = 50.0f  + pr[2]  * 950.0f;
        float k0    = 0.05f  + pr[4]  * 0.85f;
        float k1    = 0.01f  + pr[6]  * 0.49f;
        float k2    = 0.001f + pr[8]  * 0.199f;
        float lp    = 0.2f   + pr[10] * 0.8f;
        float perc  =          pr[12] * 10.0f;
        float uzl   =          pr[14] * 100.0f;
        float tt    = -2.5f  + pr[16] * 5.0f;
        float cfmax = 0.5f   + pr[18] * 9.5f;
        float cfr   =          pr[20] * 0.1f;
        float cwh   =          pr[22] * 0.2f;
        float invfc   = 1.0f / fc;
        float invlpfc = 1.0f / (lp * fc);
        float ncfrcf  = -(cfr * cfmax);
        float omk0    = 1.0f - k0;
        float k0uzl   = k0 * uzl;
        float omk1    = 1.0f - k1;

        float sp = 1e-5f, mw = 1e-5f, sm = 0.5f * fc, suz = 1e-5f, slz = 1e-5f;

        auto body = [&](float p, float tc, float pet) -> float {
            float dt   = tc - tt;
            float msn  = fmaxf(cfmax * dt, 0.0f);
            float mrf  = fmaxf(ncfrcf * dt, 0.0f);
            float rain = (dt >= 0.0f) ? p : 0.0f;
            float snow = p - rain;
            float etk  = fmaf(-invlpfc, pet, 1.0f);      // 1 - pet/(lp*fc)
            float sw   = exp2f(beta * __log2f(sm * invfc));   // <= 1 (sm<=fc)
            float omsw = 1.0f - sw;
            float sp1  = sp + snow;
            float melt = fminf(msn, sp1);
            float mw2  = mw + melt;
            float sp2  = sp1 - melt;
            float refr = fminf(mrf, mw2);
            float mw3  = mw2 - refr;
            sp = sp2 + refr;
            float mw4  = fminf(mw3, cwh * sp);
            float tosoil = mw3 - mw4;
            mw = mw4;
            float rt    = rain + tosoil;
            float sm1   = fmaf(rt, omsw, sm);            // sm + rt - rech
            float rech  = rt * sw;
            float excess = fmaxf(sm1 - fc, 0.0f);
            float sm2   = fminf(sm1, fc);
            sm = fmaxf(fmaxf(sm2 * etk, sm2 - pet), 1e-5f);   // v_max3
            float suz1 = suz + rech + excess;
            float suz2 = fmaxf(suz1 - perc, 0.0f);
            float pa   = suz1 - suz2;                    // = min(perc, suz1)
            float suz3 = fminf(suz2, fmaf(suz2, omk0, k0uzl));
            float suzn = omk1 * suz3;
            float q01  = suz2 - suzn;                    // q0 + q1
            suz = suzn;
            float slz1 = slz + pa;
            float q2   = k2 * slz1;
            slz = slz1 - q2;
            return q01 + q2;
        };

        for (int c = 0; c < SS / PD - 1; ++c) {
#pragma unroll
            for (int j = 0; j < PD; ++j) {
                float p = pb[j], tc = tb[j], pet = eb[j];
                pb[j] = x[xoff]; tb[j] = x[xoff + 1]; eb[j] = x[xoff + 2];
                xoff += 3 * GG;
                float q = body(p, tc, pet);
                if (STORE4) qsim[qoff] = q; else atomicAdd(&qsim[qoff], 0.25f * q);
                qoff += GG;
            }
        }
#pragma unroll
        for (int j = 0; j < PD; ++j) {           // peeled last chunk
            float q = body(pb[j], tb[j], eb[j]);
            if (STORE4) qsim[qoff] = q; else atomicAdd(&qsim[qoff], 0.25f * q);
            qoff += GG;
        }
    } else {
        // ---- EXP-HYDRO parameters (descale + derived constants) ----
        const float* pe = pr + 24;
        float f    =           pe[0]  * 0.1f;
        float smax = 100.0f  + pe[2]  * 1400.0f;
        float qmax = 10.0f   + pe[4]  * 40.0f;
        float df   =           pe[6]  * 5.0f;
        float tmax =           pe[8]  * 3.0f;
        float tmin = -3.0f   + pe[10] * 3.0f;
        float invsmax = 1.0f / smax;
        float fl = f * 1.44269504f;              // f * log2(e)
        float c0 = __log2f(qmax) - fl * smax;    // fold qmax into exponent

        float s0 = 1e-5f, s1 = 0.5f * smax;

        auto body = [&](float p, float tc, float pet) -> float {
            float mdf = df * fmaxf(tc - tmax, 0.0f);
            float ps  = (tc <= tmin) ? p : 0.0f;
            float prr = p - ps;
            float etk = fmaxf(fmaf(-invsmax, pet, 1.0f), 0.0f);
            float mlt = fminf(s0, mdf);
            s0 = fmaxf(s0 - mdf, 0.0f) + ps;
            float s1a = s1 + prr + mlt;
            float qspill = fmaxf(s1a - smax, 0.0f);
            float s1b = fminf(s1a, smax);
            float s1c = s1b * etk;                       // s1b - et (exact)
            float qb  = fminf(exp2f(fmaf(fl, s1c, c0)), s1c);
            s1 = s1c - qb;
            return qspill + qb;
        };

        for (int c = 0; c < SS / PD - 1; ++c) {
#pragma unroll
            for (int j = 0; j < PD; ++j) {
                float p = pb[j], tc = tb[j], pet = eb[j];
                pb[j] = x[xoff]; tb[j] = x[xoff + 1]; eb[j] = x[xoff + 2];
                xoff += 3 * GG;
                float q = body(p, tc, pet);
                if (STORE4) qsim[qoff] = q; else atomicAdd(&qsim[qoff], 0.25f * q);
                qoff += GG;
            }
        }
#pragma unroll
        for (int j = 0; j < PD; ++j) {
            float q = body(pb[j], tb[j], eb[j]);
            if (STORE4) qsim[qoff] = q; else atomicAdd(&qsim[qoff], 0.25f * q);
            qoff += GG;
        }
    }
}

// ---------------------------------------------------------------------------
// LDS-tiled route: each block owns a (RG=128 g) x (RTT=73 t) tile.
// Cooperative load of the 87-row qsum window (4 slices summed at load) into
// 44.5 KB LDS -- every qsim value read exactly once per slice (57 MB total
// vs 112 MB for the register-tiled TT=10 route). Per-g gamma-UH weights
// computed inline (uh_weights kernel dropped; gammaln cancels under the
// normalization). Column convolution from LDS: bank aliasing is 2-way
// (lane, lane+32 -> same bank, different address) which is free on CDNA4.
// ---------------------------------------------------------------------------
__global__ __launch_bounds__(RG) void hydro_route_lds(const float* __restrict__ qsim,
                                                      const float* __restrict__ raw,
                                                      float* __restrict__ out) {
    __shared__ float lds[RTT + LENF - 1][RG];    // 87 x 128 x 4B = 44.5 KB

    int gt = blockIdx.x % NGT;
    int bt = blockIdx.x / NGT;
    int g0 = gt * RG;
    int t0 = bt * RTT;
    int tl = threadIdx.x;
    int g  = g0 + tl;

    // cooperative window load: row r <-> time t0-14+r; 128 consecutive g
    // per row -> coalesced; 4 independent slice loads pipeline freely.
    bool gok = (g < GG);
#pragma unroll 4
    for (int r = 0; r < RTT + LENF - 1; ++r) {
        int tp = t0 - (LENF - 1) + r;
        float v = 0.0f;
        if (tp >= 0 && gok) {
            const float* qb = qsim + (size_t)tp * GG + g;
            v = (qb[0] + qb[QN]) + (qb[2 * QN] + qb[3 * QN]);
        }
        lds[r][tl] = v;
    }
    __syncthreads();
    if (!gok) return;

    // per-g normalized weights (0.25 instance-average folded in)
    const float logt[LENF] = {
        -0.69314718f, 0.40546511f, 0.91629073f, 1.25276297f, 1.50407740f,
         1.70474809f, 1.87180218f, 2.01490302f, 2.14006616f, 2.25129180f,
         2.35137526f, 2.44234704f, 2.52572864f, 2.60268969f, 2.67414865f };
    float a = raw[(size_t)g * 38 + 36] * 2.9f;
    float b = raw[(size_t)g * 38 + 37] * 6.5f;
    float aa = fmaxf(a, 0.0f) + 0.1f;
    float th = fmaxf(b, 0.0f) + 0.5f;
    float am1 = aa - 1.0f;
    float invth = 1.0f / th;
    float w[LENF];
    float s = 0.0f;
#pragma unroll
    for (int k = 0; k < LENF; ++k) {
        float tk = (float)k + 0.5f;
        w[k] = expf(am1 * logt[k] - tk * invth);
        s += w[k];
    }
    float ws = 0.25f / s;
#pragma unroll
    for (int k = 0; k < LENF; ++k) w[k] *= ws;

    // column convolution; writes coalesced per row
    for (int j = 0; j < RTT; ++j) {
        float acc = 0.0f;
#pragma unroll
        for (int k = 0; k < LENF; ++k)
            acc = fmaf(w[k], lds[j + (LENF - 1) - k][tl], acc);
        out[(size_t)(t0 + j) * GG + g] = acc;
    }
}

// ---------------------------------------------------------------------------
// Atomic-fallback route (only if d_ws too small for 4 slices): register-
// tiled TT=10, weights inline, qsim is a single 0.25-scaled slice.
// ---------------------------------------------------------------------------
__global__ __launch_bounds__(256) void hydro_route1(const float* __restrict__ qsim,
                                                    const float* __restrict__ raw,
                                                    float* __restrict__ out) {
    int idx = blockIdx.x * 256 + threadIdx.x;
    if (idx >= GG * (SS / TT)) return;
    int g = idx % GG;
    int c = idx / GG;
    int t0 = c * TT;

    float a = raw[(size_t)g * 38 + 36] * 2.9f;
    float b = raw[(size_t)g * 38 + 37] * 6.5f;
    float aa = fmaxf(a, 0.0f) + 0.1f;
    float th = fmaxf(b, 0.0f) + 0.5f;
    float am1 = aa - 1.0f;
    float invth = 1.0f / th;
    const float logt[LENF] = {
        -0.69314718f, 0.40546511f, 0.91629073f, 1.25276297f, 1.50407740f,
         1.70474809f, 1.87180218f, 2.01490302f, 2.14006616f, 2.25129180f,
         2.35137526f, 2.44234704f, 2.52572864f, 2.60268969f, 2.67414865f };
    float w[LENF];
    float s = 0.0f;
#pragma unroll
    for (int k = 0; k < LENF; ++k) {
        float tk = (float)k + 0.5f;
        w[k] = expf(am1 * logt[k] - tk * invth);
        s += w[k];
    }
    float scale = 1.0f / s;

    float v[TT + LENF - 1];
#pragma unroll
    for (int i = 0; i < TT + LENF - 1; ++i) {
        int tp = t0 - (LENF - 1) + i;
        v[i] = (tp >= 0) ? qsim[(size_t)tp * GG + g] : 0.0f;
    }
#pragma unroll
    for (int j = 0; j < TT; ++j) {
        float acc = 0.0f;
#pragma unroll
        for (int k = 0; k < LENF; ++k)
            acc += w[k] * v[j + (LENF - 1) - k];
        out[(size_t)(t0 + j) * GG + g] = acc * scale;
    }
}

// ---------------------------------------------------------------------------
extern "C" void kernel_launch(void* const* d_in, const int* in_sizes, int n_in,
                              void* d_out, int out_size, void* d_ws, size_t ws_size,
                              hipStream_t stream) {
    const float* x   = (const float*)d_in[0];   // (730, 4000, 3) f32
    const float* raw = (const float*)d_in[1];   // (4000, 38) f32
    float* out  = (float*)d_out;                // (730, 4000) f32
    float* qsim = (float*)d_ws;

    const size_t slices4 = 4 * QN * sizeof(float);
    int sblocks = (4 * GPAD) / 64;

    if (ws_size >= slices4) {
        hydro_scan<true><<<sblocks, 64, 0, stream>>>(x, raw, qsim);
        hydro_route_lds<<<NGT * (SS / RTT), RG, 0, stream>>>(qsim, raw, out);
    } else {
        hipMemsetAsync(qsim, 0, QN * sizeof(float), stream);
        hydro_scan<false><<<sblocks, 64, 0, stream>>>(x, raw, qsim);
        hydro_route1<<<(GG * (SS / TT) + 255) / 256, 256, 0, stream>>>(qsim, raw, out);
    }
}